// Round 5
// baseline (705.090 us; speedup 1.0000x reference)
//
#include <hip/hip_runtime.h>
#include <hip/hip_bf16.h>

typedef __hip_bfloat16 bf16;
typedef __attribute__((ext_vector_type(8))) short s8v;   // 8 bf16 = 16B
typedef __attribute__((ext_vector_type(4))) float f4v;

constexpr int S = 1024, CA = 768, CS = 384, CZ = 128, NHID = 1536;
constexpr int NBLK = 4, NHEAD = 16, DH = 48;
constexpr float EPS = 1e-5f;

#define DEV static __device__ __forceinline__

DEV float sigmoidf_(float x) { return 1.0f / (1.0f + __expf(-x)); }

DEV f4v mfma16(s8v a, s8v b, f4v c) {
  return __builtin_amdgcn_mfma_f32_16x16x32_bf16(a, b, c, 0, 0, 0);
}

DEV void gld_lds16(const void* g, void* l) {
  __builtin_amdgcn_global_load_lds((const __attribute__((address_space(1))) void*)g,
                                   (__attribute__((address_space(3))) void*)l, 16, 0, 0);
}

union U8 { s8v s; bf16 h[8]; };
union U4 { uint2 u; bf16 h[4]; };

DEV float wred_sum(float v) {
#pragma unroll
  for (int o = 32; o; o >>= 1) v += __shfl_xor(v, o);
  return v;
}

// ---------------- s prep: LN(s)->s_hat, cast->s_bf ----------------
__global__ __launch_bounds__(256) void rowln_s(const float* __restrict__ x,
                                               bf16* __restrict__ s_hat,
                                               bf16* __restrict__ s_bf) {
  constexpr int C = CS, C4 = C / 4;
  __shared__ float red[8];
  const int t = threadIdx.x;
  const size_t row = blockIdx.x;
  float4 v = make_float4(0.f, 0.f, 0.f, 0.f);
  if (t < C4) v = ((const float4*)(x + row * C))[t];
  float sum = v.x + v.y + v.z + v.w;
  float sq = v.x * v.x + v.y * v.y + v.z * v.z + v.w * v.w;
  sum = wred_sum(sum); sq = wred_sum(sq);
  const int wv = t >> 6;
  if ((t & 63) == 0) { red[2 * wv] = sum; red[2 * wv + 1] = sq; }
  __syncthreads();
  sum = red[0] + red[2] + red[4] + red[6];
  sq = red[1] + red[3] + red[5] + red[7];
  const float m = sum / C;
  const float rstd = rsqrtf(sq / C - m * m + EPS);
  if (t < C4) {
    U4 oh, ob_;
    oh.h[0] = __float2bfloat16((v.x - m) * rstd); oh.h[1] = __float2bfloat16((v.y - m) * rstd);
    oh.h[2] = __float2bfloat16((v.z - m) * rstd); oh.h[3] = __float2bfloat16((v.w - m) * rstd);
    ob_.h[0] = __float2bfloat16(v.x); ob_.h[1] = __float2bfloat16(v.y);
    ob_.h[2] = __float2bfloat16(v.z); ob_.h[3] = __float2bfloat16(v.w);
    *(uint2*)(s_hat + row * C + 4 * t) = oh.u;
    *(uint2*)(s_bf + row * C + 4 * t) = ob_.u;
  }
}

// ---------------- fused LN(a) + both adaLNs ----------------
__global__ __launch_bounds__(256) void ln_adaln2(const float* __restrict__ a,
                                                 const bf16* __restrict__ ada,
                                                 bf16* __restrict__ ah_attn,
                                                 bf16* __restrict__ ah_tr) {
  __shared__ float red[8];
  const int t = threadIdx.x;
  const size_t row = blockIdx.x;
  float4 v = make_float4(0.f, 0.f, 0.f, 0.f);
  if (t < 192) v = ((const float4*)(a + row * CA))[t];
  float sum = v.x + v.y + v.z + v.w;
  float sq = v.x * v.x + v.y * v.y + v.z * v.z + v.w * v.w;
  sum = wred_sum(sum); sq = wred_sum(sq);
  const int wv = t >> 6;
  if ((t & 63) == 0) { red[2 * wv] = sum; red[2 * wv + 1] = sq; }
  __syncthreads();
  sum = red[0] + red[2] + red[4] + red[6];
  sq = red[1] + red[3] + red[5] + red[7];
  const float m = sum / CA;
  const float rstd = rsqrtf(sq / CA - m * m + EPS);
  if (t < 192) {
    const float an[4] = {(v.x - m) * rstd, (v.y - m) * rstd, (v.z - m) * rstd, (v.w - m) * rstd};
    const bf16* ar = ada + row * 12288 + 4 * t;
    U4 g1, b1, g2, b2, o1, o2;
    g1.u = *(const uint2*)(ar);
    b1.u = *(const uint2*)(ar + 768);
    g2.u = *(const uint2*)(ar + 1536);
    b2.u = *(const uint2*)(ar + 2304);
#pragma unroll
    for (int j = 0; j < 4; ++j) {
      o1.h[j] = __float2bfloat16(sigmoidf_(__bfloat162float(g1.h[j])) * an[j] + __bfloat162float(b1.h[j]));
      o2.h[j] = __float2bfloat16(sigmoidf_(__bfloat162float(g2.h[j])) * an[j] + __bfloat162float(b2.h[j]));
    }
    *(uint2*)(ah_attn + row * CA + 4 * t) = o1.u;
    *(uint2*)(ah_tr + row * CA + 4 * t) = o2.u;
  }
}

// ---------------- grouped transpose+cvt ----------------
struct TGroup {
  const float* src[6];
  bf16* dst[6];
  const float* cs[6];
  long dstZ[6];
};

__global__ __launch_bounds__(256) void transpose_grp(TGroup g, int K, int N, int csZ) {
  __shared__ float tile[32][33];
  const int z = blockIdx.z, wsel = z >> 2, blk = z & 3;
  const float* src = g.src[wsel] + (size_t)blk * K * N;
  bf16* dst = g.dst[wsel] + (size_t)blk * g.dstZ[wsel];
  const float* cs = g.cs[wsel];
  const int k0 = blockIdx.y * 32, n0 = blockIdx.x * 32;
  const int tx = threadIdx.x & 31, ty = threadIdx.x >> 5;
#pragma unroll
  for (int q = 0; q < 4; ++q) {
    const int k = k0 + ty + 8 * q;
    float v = src[(size_t)k * N + n0 + tx];
    if (cs) v *= cs[(size_t)blk * csZ + k];
    tile[ty + 8 * q][tx] = v;
  }
  __syncthreads();
#pragma unroll
  for (int q = 0; q < 4; ++q)
    dst[(size_t)(n0 + ty + 8 * q) * K + k0 + tx] = __float2bfloat16(tile[tx][ty + 8 * q]);
}

// ---------------- prep: W2T bf16 [64][128], bias2 f32[64] ----------------
__global__ __launch_bounds__(256) void prep_w2(const float* __restrict__ ln_z_w,
                                               const float* __restrict__ ln_z_b,
                                               const float* __restrict__ wpb,
                                               bf16* __restrict__ W2T,
                                               float* __restrict__ bias2) {
  const int t = threadIdx.x;
  for (int f = t; f < 64 * CZ; f += 256) {
    const int col = f >> 7, c = f & 127, blk = col >> 4, h = col & 15;
    W2T[f] = __float2bfloat16(ln_z_w[blk * CZ + c] * wpb[(blk * CZ + c) * NHEAD + h]);
  }
  if (t < 64) {
    const int blk = t >> 4, h = t & 15;
    float sum = 0.f;
    for (int c = 0; c < CZ; ++c)
      sum += ln_z_b[blk * CZ + c] * wpb[(blk * CZ + c) * NHEAD + h];
    bias2[t] = sum;
  }
}

__global__ __launch_bounds__(256) void prep_biases(const float* __restrict__ bq,
                                                   const float* __restrict__ bsg_attn,
                                                   const float* __restrict__ bsg_tr,
                                                   float* __restrict__ biasQKVG,
                                                   float* __restrict__ biasSG) {
  const int t = blockIdx.x * 256 + threadIdx.x;
  if (t < 4 * 3072) {
    const int b = t / 3072, c = t % 3072;
    biasQKVG[t] = (c < 768) ? bq[b * 768 + c] : 0.f;
  }
  if (t < 6144) {
    const int b = t / 1536, c = t % 1536;
    biasSG[t] = (c < 768) ? bsg_attn[b * 768 + c] : bsg_tr[b * 768 + c - 768];
  }
}

// ---------------- zbias: LN(z)@W2T + bias2 + beta -> bf16 [64][S][S], MFMA ----------------
__global__ __launch_bounds__(256) void zbias_kernel(const float* __restrict__ z,
                                                    const float* __restrict__ beta,
                                                    const bf16* __restrict__ W2T,
                                                    const float* __restrict__ bias2,
                                                    bf16* __restrict__ bias_all) {
  __shared__ s8v zt8[64 * 16];
  __shared__ s8v w2s[64 * 16];
  __shared__ float betas[64][17];
  __shared__ float bias2s[64];
  __shared__ bf16 obuf[64][72];
  const int t = threadIdx.x;
  const int i = blockIdx.y, j0 = blockIdx.x * 64;
#pragma unroll
  for (int q = 0; q < 4; ++q) {
    const int u = q * 256 + t;
    const int row = u >> 4, sl = u & 15;
    w2s[row * 16 + (sl ^ (row & 7))] = *(const s8v*)(W2T + row * CZ + sl * 8);
  }
  if (t < 64) bias2s[t] = bias2[t];
  {
    const int j = t >> 2, h4 = t & 3;
    const float4 bv = *(const float4*)(beta + ((size_t)i * S + j0 + j) * NHEAD + 4 * h4);
    betas[j][4 * h4 + 0] = bv.x; betas[j][4 * h4 + 1] = bv.y;
    betas[j][4 * h4 + 2] = bv.z; betas[j][4 * h4 + 3] = bv.w;
  }
  {
    const int p = t >> 2, q = t & 3;
    const float* zr = z + ((size_t)i * S + j0 + p) * CZ + q * 32;
    float vals[32];
    float sum = 0.f, sq = 0.f;
#pragma unroll
    for (int k4 = 0; k4 < 8; ++k4) {
      const float4 xv = *(const float4*)(zr + 4 * k4);
      vals[4 * k4 + 0] = xv.x; vals[4 * k4 + 1] = xv.y;
      vals[4 * k4 + 2] = xv.z; vals[4 * k4 + 3] = xv.w;
      sum += xv.x + xv.y + xv.z + xv.w;
      sq += xv.x * xv.x + xv.y * xv.y + xv.z * xv.z + xv.w * xv.w;
    }
    sum += __shfl_xor(sum, 1); sum += __shfl_xor(sum, 2);
    sq += __shfl_xor(sq, 1); sq += __shfl_xor(sq, 2);
    const float m = sum / CZ;
    const float rstd = rsqrtf(sq / CZ - m * m + EPS);
#pragma unroll
    for (int u = 0; u < 4; ++u) {
      U8 pk;
#pragma unroll
      for (int e = 0; e < 8; ++e) pk.h[e] = __float2bfloat16((vals[8 * u + e] - m) * rstd);
      const int cu = 4 * q + u;
      zt8[p * 16 + (cu ^ (p & 7))] = pk.s;
    }
  }
  __syncthreads();
  const int lane = t & 63, wid = t >> 6;
  const int wr = wid >> 1, wc = wid & 1;
  const int ln = lane & 15, lq = lane >> 4;
  f4v acc[2][2] = {};
#pragma unroll
  for (int kk = 0; kk < 4; ++kk) {
    const int sl = (lq + 4 * kk) ^ (ln & 7);
    s8v a[2], b[2];
#pragma unroll
    for (int mi = 0; mi < 2; ++mi) a[mi] = zt8[(32 * wr + 16 * mi + ln) * 16 + sl];
#pragma unroll
    for (int ni = 0; ni < 2; ++ni) b[ni] = w2s[(32 * wc + 16 * ni + ln) * 16 + sl];
#pragma unroll
    for (int mi = 0; mi < 2; ++mi)
#pragma unroll
      for (int ni = 0; ni < 2; ++ni) acc[mi][ni] = mfma16(a[mi], b[ni], acc[mi][ni]);
  }
#pragma unroll
  for (int mi = 0; mi < 2; ++mi)
#pragma unroll
    for (int ni = 0; ni < 2; ++ni) {
      const int col = 32 * wc + 16 * ni + ln;
      const int jb = 32 * wr + 16 * mi + 4 * lq;
      U4 o4;
#pragma unroll
      for (int r = 0; r < 4; ++r)
        o4.h[r] = __float2bfloat16(acc[mi][ni][r] + bias2s[col] + betas[jb + r][col & 15]);
      *(uint2*)&obuf[col][jb] = o4.u;
    }
  __syncthreads();
  {
    const int oc = t >> 2, js = (t & 3) * 16;
    bf16* dp = bias_all + (size_t)oc * S * S + (size_t)i * S + j0 + js;
    *(s8v*)dp = *(const s8v*)&obuf[oc][js];
    *(s8v*)(dp + 8) = *(const s8v*)&obuf[oc][js + 8];
  }
}

// ---------------- 2-phase gload_lds paired GEMM (amode 0 only) ----------------
struct Gemm2Args {
  const bf16* A0[2]; int lda0[2];
  const bf16* Bt[2];
  const float* bias[2];
  void* C[2];
  int K[2];
  int nb[2];       // valid n-block count per z (early exit beyond)
  int outMode[2];  // 0: bf16 ; 1: f32 + sigmoid
  int N[2];
  bf16* vT;        // if set: z==0 cols [1536,2304) diverted to vT[n-1536][m]
};

__global__ __launch_bounds__(256) void gemm2(Gemm2Args ga) {
  const int z = blockIdx.z;
  if ((int)blockIdx.x >= ga.nb[z]) return;
  __shared__ s8v As[2][1024];
  __shared__ s8v Bs[2][1024];
  const bf16* A0 = ga.A0[z]; const int lda0 = ga.lda0[z];
  const bf16* Bt = ga.Bt[z];
  const int K = ga.K[z], N = ga.N[z];
  const int t = threadIdx.x;
  const int lane = t & 63, wid = t >> 6;
  const int wr = wid >> 1, wc = wid & 1;
  const int ln = lane & 15, lq = lane >> 4;
  const int m0 = blockIdx.y * 128, n0 = blockIdx.x * 128;
  // per-thread global source (pre-swizzled col so linear LDS dest lands swizzled)
  int rowA[4], colx[4];
#pragma unroll
  for (int q = 0; q < 4; ++q) {
    const int u = q * 256 + t, row = u >> 3, slp = u & 7;
    rowA[q] = row; colx[q] = (slp ^ (row & 7)) * 8;
  }
  auto stage = [&](int ks, int buf) {
#pragma unroll
    for (int q = 0; q < 4; ++q) {
      gld_lds16(A0 + (size_t)(m0 + rowA[q]) * lda0 + ks + colx[q], &As[buf][q * 256 + wid * 64]);
      gld_lds16(Bt + (size_t)(n0 + rowA[q]) * K + ks + colx[q], &Bs[buf][q * 256 + wid * 64]);
    }
  };
  f4v acc[4][4] = {};
  stage(0, 0);
  __syncthreads();
  int cur = 0;
  for (int ks = 0;;) {
    const int ksn = ks + 64;
    if (ksn < K) stage(ksn, cur ^ 1);
    __builtin_amdgcn_s_setprio(1);
#pragma unroll
    for (int kk = 0; kk < 2; ++kk) {
      const int sl = (lq + 4 * kk) ^ (ln & 7);
      s8v a[4], b[4];
#pragma unroll
      for (int mi = 0; mi < 4; ++mi) a[mi] = As[cur][(64 * wr + 16 * mi + ln) * 8 + sl];
#pragma unroll
      for (int ni = 0; ni < 4; ++ni) b[ni] = Bs[cur][(64 * wc + 16 * ni + ln) * 8 + sl];
#pragma unroll
      for (int mi = 0; mi < 4; ++mi)
#pragma unroll
        for (int ni = 0; ni < 4; ++ni) acc[mi][ni] = mfma16(a[mi], b[ni], acc[mi][ni]);
    }
    __builtin_amdgcn_s_setprio(0);
    ks = ksn;
    if (ks >= K) break;
    __syncthreads();
    cur ^= 1;
  }
  const bool vdiv = (ga.vT != nullptr) && (z == 0) && (n0 >= 1536) && (n0 < 2304);
  const int om = ga.outMode[z];
#pragma unroll
  for (int ni = 0; ni < 4; ++ni) {
    const int n = n0 + 64 * wc + 16 * ni + ln;
    const float bv = ga.bias[z] ? ga.bias[z][n] : 0.f;
#pragma unroll
    for (int mi = 0; mi < 4; ++mi) {
      const int mb = m0 + 64 * wr + 16 * mi + 4 * lq;
      if (vdiv) {
        U4 o4;
#pragma unroll
        for (int r = 0; r < 4; ++r) o4.h[r] = __float2bfloat16(acc[mi][ni][r] + bv);
        *(uint2*)(ga.vT + (size_t)(n - 1536) * S + mb) = o4.u;
      } else if (om == 0) {
        bf16* C = (bf16*)ga.C[z];
#pragma unroll
        for (int r = 0; r < 4; ++r)
          C[(size_t)(mb + r) * N + n] = __float2bfloat16(acc[mi][ni][r] + bv);
      } else {
        float* C = (float*)ga.C[z];
#pragma unroll
        for (int r = 0; r < 4; ++r)
          C[(size_t)(mb + r) * N + n] = sigmoidf_(acc[mi][ni][r] + bv);
      }
    }
  }
}

// ---------------- reg-staged paired GEMM with A-combine (for wo/wout) ----------------
struct GemmPairArgs {
  const bf16* A0[2]; int lda0[2];
  const bf16* A1[2]; int lda1[2];
  const bf16* Bt[2];
  const float* bias[2];
  bf16* C[2];
  int K[2]; int amode[2];
};

DEV s8v combineRT(s8v x, s8v y, int amode) {
  U8 ux, uy, r;
  ux.s = x; uy.s = y;
#pragma unroll
  for (int j = 0; j < 8; ++j) {
    const float fx = __bfloat162float(ux.h[j]);
    const float fy = __bfloat162float(uy.h[j]);
    const float tt = sigmoidf_(fx);
    r.h[j] = __float2bfloat16((amode == 2 ? fx * tt : tt) * fy);
  }
  return r.s;
}

__global__ __launch_bounds__(256) void gemm_pair(GemmPairArgs ga, int N) {
  __shared__ s8v As[128 * 8];
  __shared__ s8v Bs[128 * 8];
  const int z = blockIdx.z;
  const bf16* A0 = ga.A0[z]; const int lda0 = ga.lda0[z];
  const bf16* A1 = ga.A1[z]; const int lda1 = ga.lda1[z];
  const bf16* Bt = ga.Bt[z];
  const float* bias = ga.bias[z];
  bf16* C = ga.C[z];
  const int K = ga.K[z], amode = ga.amode[z];
  const int t = threadIdx.x;
  const int lane = t & 63, wid = t >> 6;
  const int wr = wid >> 1, wc = wid & 1;
  const int ln = lane & 15, lq = lane >> 4;
  const int m0 = blockIdx.y * 128, n0 = blockIdx.x * 128;
  int rowS[4], slS[4], swz[4];
#pragma unroll
  for (int q = 0; q < 4; ++q) {
    const int u = q * 256 + t;
    rowS[q] = u >> 3; slS[q] = u & 7;
    swz[q] = rowS[q] * 8 + (slS[q] ^ (rowS[q] & 7));
  }
  f4v acc[4][4] = {};
  s8v ra[4], ra2[4], rb[4];
#pragma unroll
  for (int q = 0; q < 4; ++q) {
    ra[q] = *(const s8v*)(A0 + (size_t)(m0 + rowS[q]) * lda0 + slS[q] * 8);
    if (amode != 0) ra2[q] = *(const s8v*)(A1 + (size_t)(m0 + rowS[q]) * lda1 + slS[q] * 8);
    rb[q] = *(const s8v*)(Bt + (size_t)(n0 + rowS[q]) * K + slS[q] * 8);
  }
  for (int ks = 0;;) {
    __syncthreads();
#pragma unroll
    for (int q = 0; q < 4; ++q) {
      As[swz[q]] = (amode == 0) ? ra[q] : combineRT(ra[q], ra2[q], amode);
      Bs[swz[q]] = rb[q];
    }
    const int ksn = ks + 64;
    if (ksn < K) {
#pragma unroll
      for (int q = 0; q < 4; ++q) {
        ra[q] = *(const s8v*)(A0 + (size_t)(m0 + rowS[q]) * lda0 + ksn + slS[q] * 8);
        if (amode != 0) ra2[q] = *(const s8v*)(A1 + (size_t)(m0 + rowS[q]) * lda1 + ksn + slS[q] * 8);
        rb[q] = *(const s8v*)(Bt + (size_t)(n0 + rowS[q]) * K + ksn + slS[q] * 8);
      }
    }
    __syncthreads();
#pragma unroll
    for (int kk = 0; kk < 2; ++kk) {
      const int sl = (lq + 4 * kk) ^ (ln & 7);
      s8v a[4], b[4];
#pragma unroll
      for (int mi = 0; mi < 4; ++mi) a[mi] = As[(64 * wr + 16 * mi + ln) * 8 + sl];
#pragma unroll
      for (int ni = 0; ni < 4; ++ni) b[ni] = Bs[(64 * wc + 16 * ni + ln) * 8 + sl];
#pragma unroll
      for (int mi = 0; mi < 4; ++mi)
#pragma unroll
        for (int ni = 0; ni < 4; ++ni) acc[mi][ni] = mfma16(a[mi], b[ni], acc[mi][ni]);
    }
    ks = ksn;
    if (ks >= K) break;
  }
#pragma unroll
  for (int ni = 0; ni < 4; ++ni) {
    const int n = n0 + 64 * wc + 16 * ni + ln;
    const float bv = bias ? bias[n] : 0.f;
#pragma unroll
    for (int mi = 0; mi < 4; ++mi) {
      const int mb = m0 + 64 * wr + 16 * mi + 4 * lq;
#pragma unroll
      for (int r = 0; r < 4; ++r)
        C[(size_t)(mb + r) * N + n] = __float2bfloat16(acc[mi][ni][r] + bv);
    }
  }
}

// ---------------- flash attention: 128 threads, 32 q-rows/block ----------------
__global__ __launch_bounds__(128) void flash_attn(const bf16* __restrict__ qkvg,
                                                  const bf16* __restrict__ vT,
                                                  const bf16* __restrict__ bias_all,
                                                  bf16* __restrict__ ob, int blk) {
  __shared__ s8v Qs[32 * 8];
  __shared__ s8v Ks[2][64 * 8];
  __shared__ s8v Vs[2][48 * 8];
  __shared__ s8v Bs[2][32 * 8];
  __shared__ bf16 PwB[2 * 1024];
  __shared__ float facL[2][16];
  __shared__ float linvL[2][16];
  const int t = threadIdx.x;
  const int lane = t & 63, w = t >> 6;  // 2 waves
  const int ln = lane & 15, lq = lane >> 4;
  const int h = blockIdx.y, i0 = blockIdx.x * 32;
  const bf16* bp = bias_all + (size_t)(blk * NHEAD + h) * S * S;
  const float scale = 0.14433756729740643f;

#pragma unroll
  for (int uu = 0; uu < 2; ++uu) {
    const int u = t + 128 * uu, row = u >> 3, sl = u & 7;
    s8v qv{};
    if (sl < 6) qv = *(const s8v*)(qkvg + (size_t)(i0 + row) * 3072 + h * DH + sl * 8);
    Qs[row * 8 + (sl ^ (row & 7))] = qv;
  }

  s8v kr[4], br[2], vr[3];
  auto prefetch = [&](int jt) {
    const int j0 = jt * 64;
#pragma unroll
    for (int uu = 0; uu < 4; ++uu) {
      const int u = t + 128 * uu, row = u >> 3, sl = u & 7;
      s8v kv{};
      if (sl < 6) kv = *(const s8v*)(qkvg + (size_t)(j0 + row) * 3072 + 768 + h * DH + sl * 8);
      kr[uu] = kv;
    }
#pragma unroll
    for (int uu = 0; uu < 2; ++uu) {
      const int u = t + 128 * uu, row = u >> 3, sl = u & 7;
      br[uu] = *(const s8v*)(bp + (size_t)(i0 + row) * S + j0 + sl * 8);
    }
#pragma unroll
    for (int uu = 0; uu < 3; ++uu) {
      const int u = t + 128 * uu, d = u >> 3, sl = u & 7;
      vr[uu] = *(const s8v*)(vT + (size_t)(h * DH + d) * S + j0 + sl * 8);
    }
  };
  auto store_tiles = [&](int pb) {
#pragma unroll
    for (int uu = 0; uu < 4; ++uu) {
      const int u = t + 128 * uu, row = u >> 3, sl = u & 7;
      Ks[pb][row * 8 + (sl ^ (row & 7))] = kr[uu];
    }
#pragma unroll
    for (int uu = 0; uu < 2; ++uu) {
      const int u = t + 128 * uu, row = u >> 3, sl = u & 7;
      Bs[pb][row * 8 + (sl ^ (row & 7))] = br[uu];
    }
#pragma unroll
    for (int uu = 0; uu < 3; ++uu) {
      const int u = t + 128 * uu, d = u >> 3, sl = u & 7;
      Vs[pb][d * 8 + (sl ^ (d & 7))] = vr[uu];
    }
  };

  float m_run = -3e30f, l_run = 0.f;
  f4v acc_o[3] = {};
  bf16* pw = PwB + w * 1024;

  prefetch(0);
  for (int jt = 0; jt < 16; ++jt) {
    const int pb = jt & 1;
    __syncthreads();
    store_tiles(pb);
    __syncthreads();
    if (jt < 15) prefetch(jt + 1);
    float p[4][4];
    float tmax = -3e30f;
    __builtin_amdgcn_s_setprio(1);
#pragma unroll
    for (int ja = 0; ja < 4; ++ja) {
      f4v accs = {};
#pragma unroll
      for (int ks2 = 0; ks2 < 2; ++ks2) {
        const int sl = (lq + 4 * ks2) ^ (ln & 7);
        const s8v a = Ks[pb][(16 * ja + ln) * 8 + sl];
        const s8v b = Qs[(16 * w + ln) * 8 + sl];
        accs = mfma16(a, b, accs);
      }
      const int jq = 4 * ja + lq;
      const int pu = jq >> 1;
      U4 bv;
      bv.u = *(const uint2*)((const bf16*)(&Bs[pb][0]) +
                             (((16 * w + ln) * 8 + (pu ^ (ln & 7))) * 8 + (jq & 1) * 4));
#pragma unroll
      for (int r = 0; r < 4; ++r) {
        p[ja][r] = accs[r] * scale + __bfloat162float(bv.h[r]);
        tmax = fmaxf(tmax, p[ja][r]);
      }
    }
    __builtin_amdgcn_s_setprio(0);
    tmax = fmaxf(tmax, __shfl_xor(tmax, 16));
    tmax = fmaxf(tmax, __shfl_xor(tmax, 32));
    const float m_new = fmaxf(m_run, tmax);
    const float fac = __expf(m_run - m_new);
    m_run = m_new;
    float psum = 0.f;
#pragma unroll
    for (int ja = 0; ja < 4; ++ja)
#pragma unroll
      for (int r = 0; r < 4; ++r) {
        p[ja][r] = __expf(p[ja][r] - m_new);
        psum += p[ja][r];
      }
    psum += __shfl_xor(psum, 16);
    psum += __shfl_xor(psum, 32);
    l_run = l_run * fac + psum;
    if (lq == 0) facL[w][ln] = fac;
#pragma unroll
    for (int ja = 0; ja < 4; ++ja) {
      const int ju = 4 * ja + lq;
      const int ph = ju ^ ((ln & 7) << 1);
      U4 pk;
#pragma unroll
      for (int r = 0; r < 4; ++r) pk.h[r] = __float2bfloat16(p[ja][r]);
      *(uint2*)(pw + ln * 64 + ph * 4) = pk.u;
    }
    asm volatile("s_waitcnt lgkmcnt(0)" ::: "memory");
    __builtin_amdgcn_sched_barrier(0);
    const float4 fv = *(const float4*)&facL[w][4 * lq];
#pragma unroll
    for (int ni = 0; ni < 3; ++ni) {
      acc_o[ni][0] *= fv.x; acc_o[ni][1] *= fv.y;
      acc_o[ni][2] *= fv.z; acc_o[ni][3] *= fv.w;
    }
    __builtin_amdgcn_s_setprio(1);
#pragma unroll
    for (int ks2 = 0; ks2 < 2; ++ks2) {
      const int pu0 = (2 * lq + 8 * ks2) ^ ((ln & 7) << 1);
      const s8v pa = *(const s8v*)(pw + ln * 64 + pu0 * 4);
      const int slv = (lq + 4 * ks2) ^ (ln & 7);
#pragma unroll
      for (int ni = 0; ni < 3; ++ni) {
        const s8v vb = Vs[pb][(16 * ni + ln) * 8 + slv];
        acc_o[ni] = mfma16(pa, vb, acc_o[ni]);
      }
    }
    __builtin_amdgcn_s_setprio(0);
  }
  if (lq == 0) linvL[w][ln] = 1.0f / l_run;
  asm volatile("s_waitcnt lgkmcnt(0)" ::: "memory");
  __builtin_amdgcn_sched_barrier(0);
  const float4 lv = *(const float4*)&linvL[w][4 * lq];
  const float lvr[4] = {lv.x, lv.y, lv.z, lv.w};
#pragma unroll
  for (int ni = 0; ni < 3; ++ni)
#pragma unroll
    for (int r = 0; r < 4; ++r) {
      const int m = i0 + 16 * w + 4 * lq + r;
      ob[(size_t)m * CA + h * DH + 16 * ni + ln] = __float2bfloat16(acc_o[ni][r] * lvr[r]);
    }
}

// ---------------- final: out = sgA*att + sgT*tr (f32 out) ----------------
__global__ __launch_bounds__(256) void ew_final(const float* __restrict__ sg,
                                                const bf16* __restrict__ att,
                                                const bf16* __restrict__ tr,
                                                float* __restrict__ out) {
  const int i = blockIdx.x * 256 + threadIdx.x;
  const int row = i / 192, col = (i % 192) * 4;
  const float4 sa = *(const float4*)(sg + (size_t)row * 6144 + col);
  const float4 st = *(const float4*)(sg + (size_t)row * 6144 + 768 + col);
  U4 av, tv;
  av.u = *(const uint2*)(att + (size_t)row * CA + col);
  tv.u = *(const uint2*)(tr + (size_t)row * CA + col);
  float4 o;
  o.x = sa.x * __bfloat162float(av.h[0]) + st.x * __bfloat162float(tv.h[0]);
  o.y = sa.y * __bfloat162float(av.h[1]) + st.y * __bfloat162float(tv.h[1]);
  o.z = sa.z * __bfloat162float(av.h[2]) + st.z * __bfloat162float(tv.h[2]);
  o.w = sa.w * __bfloat162float(av.h[3]) + st.w * __bfloat162float(tv.h[3]);
  *(float4*)(out + (size_t)row * CA + col) = o;
}

__global__ void fill_kernel(float* p, int n, float v) {
  const int i = blockIdx.x * 256 + threadIdx.x;
  if (i < n) p[i] = v;
}

extern "C" void kernel_launch(void* const* d_in, const int* in_sizes, int n_in,
                              void* d_out, int out_size, void* d_ws, size_t ws_size,
                              hipStream_t stream) {
  (void)in_sizes; (void)n_in;
  const float* a_in = (const float*)d_in[0];
  const float* s_in = (const float*)d_in[1];
  const float* z_in = (const float*)d_in[2];
  const float* beta = (const float*)d_in[3];
  const float* ln_s_w_attn = (const float*)d_in[4];
  const float* wg_attn = (const float*)d_in[5];
  const float* wb_attn = (const float*)d_in[6];
  const float* wq = (const float*)d_in[7];
  const float* bq = (const float*)d_in[8];
  const float* wk = (const float*)d_in[9];
  const float* wv = (const float*)d_in[10];
  const float* ln_z_w = (const float*)d_in[11];
  const float* ln_z_b = (const float*)d_in[12];
  const float* wpb = (const float*)d_in[13];
  const float* wgate = (const float*)d_in[14];
  const float* wo = (const float*)d_in[15];
  const float* wsg_attn = (const float*)d_in[16];
  const float* bsg_attn = (const float*)d_in[17];
  const float* ln_s_w_tr = (const float*)d_in[18];
  const float* wg_tr = (const float*)d_in[19];
  const float* wb_tr = (const float*)d_in[20];
  const float* w_swish = (const float*)d_in[21];
  const float* w_gate2 = (const float*)d_in[22];
  const float* wsg_tr = (const float*)d_in[23];
  const float* bsg_tr = (const float*)d_in[24];
  const float* w_out = (const float*)d_in[25];

  char* wp = (char*)d_ws;
  size_t used = 0;
  auto alloc = [&](size_t bytes) -> void* {
    void* p = wp + used;
    used += (bytes + 255) & ~(size_t)255;
    return p;
  };
  bf16* bias_all = (bf16*)alloc((size_t)64 * S * S * 2);
  bf16* WT_ada = (bf16*)alloc((size_t)4 * 3072 * 384 * 2);
  bf16* WT_sg = (bf16*)alloc((size_t)4 * 1536 * 384 * 2);
  bf16* WT_qkvg = (bf16*)alloc((size_t)4 * 3072 * 768 * 2);
  bf16* WT_wo = (bf16*)alloc((size_t)4 * 768 * 768 * 2);
  bf16* WT_mlp = (bf16*)alloc((size_t)4 * 3072 * 768 * 2);
  bf16* WT_wout = (bf16*)alloc((size_t)4 * 768 * 1536 * 2);
  float* biasQKVG = (float*)alloc(4 * 3072 * 4);
  float* biasSG = (float*)alloc(6144 * 4);
  bf16* W2T = (bf16*)alloc(64 * 128 * 2);
  float* bias2 = (float*)alloc(64 * 4);
  bf16* ada_all = (bf16*)alloc((size_t)S * 12288 * 2);
  float* sg_all = (float*)alloc((size_t)S * 6144 * 4);
  bf16* s_hat = (bf16*)alloc((size_t)S * CS * 2);
  bf16* s_bf = (bf16*)alloc((size_t)S * CS * 2);
  float* a_buf = (float*)alloc((size_t)S * CA * 4);
  bf16* ah_attn = (bf16*)alloc((size_t)S * CA * 2);
  bf16* ah_tr = (bf16*)alloc((size_t)S * CA * 2);
  bf16* qkvg = (bf16*)alloc((size_t)S * 3072 * 2);
  bf16* vT = (bf16*)alloc((size_t)CA * S * 2);
  bf16* ob = (bf16*)alloc((size_t)S * CA * 2);
  bf16* att = (bf16*)alloc((size_t)S * CA * 2);
  bf16* swg = (bf16*)alloc((size_t)S * 3072 * 2);
  bf16* trout = (bf16*)alloc((size_t)S * CA * 2);
  if (used > ws_size) {
    fill_kernel<<<(out_size + 255) / 256, 256, 0, stream>>>((float*)d_out, out_size, 12345.0f);
    return;
  }

  const dim3 B256(256);

  prep_w2<<<1, B256, 0, stream>>>(ln_z_w, ln_z_b, wpb, W2T, bias2);
  prep_biases<<<48, B256, 0, stream>>>(bq, bsg_attn, bsg_tr, biasQKVG, biasSG);

  {  // group 1: K=384, N=768 (ada x4 + sg x2)
    TGroup g{};
    g.src[0] = wg_attn;  g.dst[0] = WT_ada + (size_t)0 * 384;    g.cs[0] = ln_s_w_attn; g.dstZ[0] = 3072 * 384;
    g.src[1] = wb_attn;  g.dst[1] = WT_ada + (size_t)768 * 384;  g.cs[1] = ln_s_w_attn; g.dstZ[1] = 3072 * 384;
    g.src[2] = wg_tr;    g.dst[2] = WT_ada + (size_t)1536 * 384; g.cs[2] = ln_s_w_tr;   g.dstZ[2] = 3072 * 384;
    g.src[3] = wb_tr;    g.dst[3] = WT_ada + (size_t)2304 * 384; g.cs[3] = ln_s_w_tr;   g.dstZ[3] = 3072 * 384;
    g.src[4] = wsg_attn; g.dst[4] = WT_sg + (size_t)0 * 384;     g.cs[4] = nullptr;     g.dstZ[4] = 1536 * 384;
    g.src[5] = wsg_tr;   g.dst[5] = WT_sg + (size_t)768 * 384;   g.cs[5] = nullptr;     g.dstZ[5] = 1536 * 384;
    transpose_grp<<<dim3(24, 12, 24), B256, 0, stream>>>(g, 384, 768, CS);
  }
  {  // group 2: K=768, N=768 (wq,wk,wv,wgate,wo)
    TGroup g{};
    g.src[0] = wq;    g.dst[0] = WT_qkvg + (size_t)0 * 768;    g.dstZ[0] = 3072 * 768;
    g.src[1] = wk;    g.dst[1] = WT_qkvg + (size_t)768 * 768;  g.dstZ[1] = 3072 * 768;
    g.src[2] = wv;    g.dst[2] = WT_qkvg + (size_t)1536 * 768; g.dstZ[2] = 3072 * 768;
    g.src[3] = wgate; g.dst[3] = WT_qkvg + (size_t)2304 * 768; g.dstZ[3] = 3072 * 768;
    g.src[4] = wo;    g.dst[4] = WT_wo;                        g.dstZ[4] = 768 * 768;
    transpose_grp<<<dim3(24, 24, 20), B256, 0, stream>>>(g, 768, 768, 0);
  }
  {  // group 3: K=768, N=1536 (w_swish, w_gate2)
    TGroup g{};
    g.src[0] = w_swish; g.dst[0] = WT_mlp + (size_t)0 * 768;    g.dstZ[0] = 3072 * 768;
    g.src[1] = w_gate2; g.dst[1] = WT_mlp + (size_t)1536 * 768; g.dstZ[1] = 3072 * 768;
    transpose_grp<<<dim3(48, 24, 8), B256, 0, stream>>>(g, 768, 1536, 0);
  }
  {  // group 4: K=1536, N=768 (w_out)
    TGroup g{};
    g.src[0] = w_out; g.dst[0] = WT_wout; g.dstZ[0] = 768 * 1536;
    transpose_grp<<<dim3(24, 48, 4), B256, 0, stream>>>(g, 1536, 768, 0);
  }

  rowln_s<<<S, B256, 0, stream>>>(s_in, s_hat, s_bf);
  zbias_kernel<<<dim3(16, 1024), B256, 0, stream>>>(z_in, beta, W2T, bias2, bias_all);

  {  // hoisted: z0 ada (N=12288), z1 sg (N=6144, sigmoid, f32)
    Gemm2Args ga{};
    ga.A0[0] = s_hat; ga.lda0[0] = 384; ga.Bt[0] = WT_ada; ga.bias[0] = nullptr;
    ga.C[0] = ada_all; ga.K[0] = 384; ga.nb[0] = 96; ga.outMode[0] = 0; ga.N[0] = 12288;
    ga.A0[1] = s_bf; ga.lda0[1] = 384; ga.Bt[1] = WT_sg; ga.bias[1] = biasSG;
    ga.C[1] = sg_all; ga.K[1] = 384; ga.nb[1] = 48; ga.outMode[1] = 1; ga.N[1] = 6144;
    ga.vT = nullptr;
    gemm2<<<dim3(96, 8, 2), B256, 0, stream>>>(ga);
  }

  const float* a_cur = a_in;
  for (int b = 0; b < NBLK; ++b) {
    ln_adaln2<<<S, B256, 0, stream>>>(a_cur, ada_all + (size_t)b * 3072, ah_attn, ah_tr);
    {  // z0 qkvg (with fused vT divert), z1 mlp(swg)
      Gemm2Args ga{};
      ga.A0[0] = ah_attn; ga.lda0[0] = 768; ga.Bt[0] = WT_qkvg + (size_t)b * 3072 * 768;
      ga.bias[0] = biasQKVG + b * 3072; ga.C[0] = qkvg; ga.K[0] = 768; ga.nb[0] = 24;
      ga.outMode[0] = 0; ga.N[0] = 3072;
      ga.A0[1] = ah_tr; ga.lda0[1] = 768; ga.Bt[1] = WT_mlp + (size_t)b * 3072 * 768;
      ga.bias[1] = nullptr; ga.C[1] = swg; ga.K[1] = 768; ga.nb[1] = 24;
      ga.outMode[1] = 0; ga.N[1] = 3072;
      ga.vT = vT;
      gemm2<<<dim3(24, 8, 2), B256, 0, stream>>>(ga);
    }
    flash_attn<<<dim3(32, 16), dim3(128), 0, stream>>>(qkvg, vT, bias_all, ob, b);
    {  // z0 att = (sig(gate)*ob)@wo ; z1 trout = swiglu(swg)@w_out
      GemmPairArgs ga{};
      ga.A0[0] = qkvg + 2304; ga.lda0[0] = 3072; ga.A1[0] = ob; ga.lda1[0] = 768;
      ga.Bt[0] = WT_wo + (size_t)b * 768 * 768; ga.bias[0] = nullptr;
      ga.C[0] = att; ga.K[0] = 768; ga.amode[0] = 1;
      ga.A0[1] = swg; ga.lda0[1] = 3072; ga.A1[1] = swg + 1536; ga.lda1[1] = 3072;
      ga.Bt[1] = WT_wout + (size_t)b * 768 * 1536; ga.bias[1] = nullptr;
      ga.C[1] = trout; ga.K[1] = 1536; ga.amode[1] = 2;
      gemm_pair<<<dim3(6, 8, 2), B256, 0, stream>>>(ga, 768);
    }
    float* a_next = (b == NBLK - 1) ? (float*)d_out : a_buf;
    ew_final<<<768, B256, 0, stream>>>(sg_all + (size_t)b * 1536, att, trout, a_next);
    a_cur = a_next;
  }
}

// Round 6
// 676.604 us; speedup vs baseline: 1.0421x; 1.0421x over previous
//
#include <hip/hip_runtime.h>
#include <hip/hip_bf16.h>

typedef __hip_bfloat16 bf16;
typedef __attribute__((ext_vector_type(8))) short s8v;   // 8 bf16 = 16B
typedef __attribute__((ext_vector_type(4))) float f4v;

constexpr int S = 1024, CA = 768, CS = 384, CZ = 128, NHID = 1536;
constexpr int NBLK = 4, NHEAD = 16, DH = 48;
constexpr float EPS = 1e-5f;

#define DEV static __device__ __forceinline__

DEV float sigmoidf_(float x) { return 1.0f / (1.0f + __expf(-x)); }

DEV f4v mfma16(s8v a, s8v b, f4v c) {
  return __builtin_amdgcn_mfma_f32_16x16x32_bf16(a, b, c, 0, 0, 0);
}

DEV void gld_lds16(const void* g, void* l) {
  __builtin_amdgcn_global_load_lds((const __attribute__((address_space(1))) void*)g,
                                   (__attribute__((address_space(3))) void*)l, 16, 0, 0);
}

union U8 { s8v s; bf16 h[8]; };
union U4 { uint2 u; bf16 h[4]; };

DEV float wred_sum(float v) {
#pragma unroll
  for (int o = 32; o; o >>= 1) v += __shfl_xor(v, o);
  return v;
}

// ---------------- s prep: LN(s)->s_hat, cast->s_bf ----------------
__global__ __launch_bounds__(256) void rowln_s(const float* __restrict__ x,
                                               bf16* __restrict__ s_hat,
                                               bf16* __restrict__ s_bf) {
  constexpr int C = CS, C4 = C / 4;
  __shared__ float red[8];
  const int t = threadIdx.x;
  const size_t row = blockIdx.x;
  float4 v = make_float4(0.f, 0.f, 0.f, 0.f);
  if (t < C4) v = ((const float4*)(x + row * C))[t];
  float sum = v.x + v.y + v.z + v.w;
  float sq = v.x * v.x + v.y * v.y + v.z * v.z + v.w * v.w;
  sum = wred_sum(sum); sq = wred_sum(sq);
  const int wv = t >> 6;
  if ((t & 63) == 0) { red[2 * wv] = sum; red[2 * wv + 1] = sq; }
  __syncthreads();
  sum = red[0] + red[2] + red[4] + red[6];
  sq = red[1] + red[3] + red[5] + red[7];
  const float m = sum / C;
  const float rstd = rsqrtf(sq / C - m * m + EPS);
  if (t < C4) {
    U4 oh, ob_;
    oh.h[0] = __float2bfloat16((v.x - m) * rstd); oh.h[1] = __float2bfloat16((v.y - m) * rstd);
    oh.h[2] = __float2bfloat16((v.z - m) * rstd); oh.h[3] = __float2bfloat16((v.w - m) * rstd);
    ob_.h[0] = __float2bfloat16(v.x); ob_.h[1] = __float2bfloat16(v.y);
    ob_.h[2] = __float2bfloat16(v.z); ob_.h[3] = __float2bfloat16(v.w);
    *(uint2*)(s_hat + row * C + 4 * t) = oh.u;
    *(uint2*)(s_bf + row * C + 4 * t) = ob_.u;
  }
}

// ---------------- fused LN(a) + both adaLNs (block 0 entry) ----------------
__global__ __launch_bounds__(256) void ln_adaln2(const float* __restrict__ a,
                                                 const bf16* __restrict__ ada,
                                                 bf16* __restrict__ ah_attn,
                                                 bf16* __restrict__ ah_tr) {
  __shared__ float red[8];
  const int t = threadIdx.x;
  const size_t row = blockIdx.x;
  float4 v = make_float4(0.f, 0.f, 0.f, 0.f);
  if (t < 192) v = ((const float4*)(a + row * CA))[t];
  float sum = v.x + v.y + v.z + v.w;
  float sq = v.x * v.x + v.y * v.y + v.z * v.z + v.w * v.w;
  sum = wred_sum(sum); sq = wred_sum(sq);
  const int wv = t >> 6;
  if ((t & 63) == 0) { red[2 * wv] = sum; red[2 * wv + 1] = sq; }
  __syncthreads();
  sum = red[0] + red[2] + red[4] + red[6];
  sq = red[1] + red[3] + red[5] + red[7];
  const float m = sum / CA;
  const float rstd = rsqrtf(sq / CA - m * m + EPS);
  if (t < 192) {
    const float an[4] = {(v.x - m) * rstd, (v.y - m) * rstd, (v.z - m) * rstd, (v.w - m) * rstd};
    const bf16* ar = ada + row * 12288 + 4 * t;
    U4 g1, b1, g2, b2, o1, o2;
    g1.u = *(const uint2*)(ar);
    b1.u = *(const uint2*)(ar + 768);
    g2.u = *(const uint2*)(ar + 1536);
    b2.u = *(const uint2*)(ar + 2304);
#pragma unroll
    for (int j = 0; j < 4; ++j) {
      o1.h[j] = __float2bfloat16(sigmoidf_(__bfloat162float(g1.h[j])) * an[j] + __bfloat162float(b1.h[j]));
      o2.h[j] = __float2bfloat16(sigmoidf_(__bfloat162float(g2.h[j])) * an[j] + __bfloat162float(b2.h[j]));
    }
    *(uint2*)(ah_attn + row * CA + 4 * t) = o1.u;
    *(uint2*)(ah_tr + row * CA + 4 * t) = o2.u;
  }
}

// ---------------- fused: a=sgA*att+sgT*tr ; LN(a) ; adaLN for NEXT block ----------------
__global__ __launch_bounds__(256) void final_adaln(const float* __restrict__ sg,   // +b*1536, ld 6144
                                                   const bf16* __restrict__ att,
                                                   const bf16* __restrict__ tr,
                                                   const bf16* __restrict__ ada,   // +(b+1)*3072
                                                   bf16* __restrict__ ah_attn,
                                                   bf16* __restrict__ ah_tr) {
  __shared__ float red[8];
  const int t = threadIdx.x;
  const size_t row = blockIdx.x;
  float o[4] = {0.f, 0.f, 0.f, 0.f};
  if (t < 192) {
    const float4 sa = *(const float4*)(sg + row * 6144 + 4 * t);
    const float4 st = *(const float4*)(sg + row * 6144 + 768 + 4 * t);
    U4 av, tv;
    av.u = *(const uint2*)(att + row * CA + 4 * t);
    tv.u = *(const uint2*)(tr + row * CA + 4 * t);
    o[0] = sa.x * __bfloat162float(av.h[0]) + st.x * __bfloat162float(tv.h[0]);
    o[1] = sa.y * __bfloat162float(av.h[1]) + st.y * __bfloat162float(tv.h[1]);
    o[2] = sa.z * __bfloat162float(av.h[2]) + st.z * __bfloat162float(tv.h[2]);
    o[3] = sa.w * __bfloat162float(av.h[3]) + st.w * __bfloat162float(tv.h[3]);
  }
  float sum = o[0] + o[1] + o[2] + o[3];
  float sq = o[0] * o[0] + o[1] * o[1] + o[2] * o[2] + o[3] * o[3];
  sum = wred_sum(sum); sq = wred_sum(sq);
  const int wv = t >> 6;
  if ((t & 63) == 0) { red[2 * wv] = sum; red[2 * wv + 1] = sq; }
  __syncthreads();
  sum = red[0] + red[2] + red[4] + red[6];
  sq = red[1] + red[3] + red[5] + red[7];
  const float m = sum / CA;
  const float rstd = rsqrtf(sq / CA - m * m + EPS);
  if (t < 192) {
    const bf16* ar = ada + row * 12288 + 4 * t;
    U4 g1, b1, g2, b2, o1, o2;
    g1.u = *(const uint2*)(ar);
    b1.u = *(const uint2*)(ar + 768);
    g2.u = *(const uint2*)(ar + 1536);
    b2.u = *(const uint2*)(ar + 2304);
#pragma unroll
    for (int j = 0; j < 4; ++j) {
      const float an = (o[j] - m) * rstd;
      o1.h[j] = __float2bfloat16(sigmoidf_(__bfloat162float(g1.h[j])) * an + __bfloat162float(b1.h[j]));
      o2.h[j] = __float2bfloat16(sigmoidf_(__bfloat162float(g2.h[j])) * an + __bfloat162float(b2.h[j]));
    }
    *(uint2*)(ah_attn + row * CA + 4 * t) = o1.u;
    *(uint2*)(ah_tr + row * CA + 4 * t) = o2.u;
  }
}

// ---------------- grouped transpose+cvt ----------------
struct TGroup {
  const float* src[6];
  bf16* dst[6];
  const float* cs[6];
  long dstZ[6];
};

__global__ __launch_bounds__(256) void transpose_grp(TGroup g, int K, int N, int csZ) {
  __shared__ float tile[32][33];
  const int z = blockIdx.z, wsel = z >> 2, blk = z & 3;
  const float* src = g.src[wsel] + (size_t)blk * K * N;
  bf16* dst = g.dst[wsel] + (size_t)blk * g.dstZ[wsel];
  const float* cs = g.cs[wsel];
  const int k0 = blockIdx.y * 32, n0 = blockIdx.x * 32;
  const int tx = threadIdx.x & 31, ty = threadIdx.x >> 5;
#pragma unroll
  for (int q = 0; q < 4; ++q) {
    const int k = k0 + ty + 8 * q;
    float v = src[(size_t)k * N + n0 + tx];
    if (cs) v *= cs[(size_t)blk * csZ + k];
    tile[ty + 8 * q][tx] = v;
  }
  __syncthreads();
#pragma unroll
  for (int q = 0; q < 4; ++q)
    dst[(size_t)(n0 + ty + 8 * q) * K + k0 + tx] = __float2bfloat16(tile[tx][ty + 8 * q]);
}

// ---------------- merged prep: W2T/bias2 + bias tables ----------------
__global__ __launch_bounds__(256) void prep_all(const float* __restrict__ ln_z_w,
                                                const float* __restrict__ ln_z_b,
                                                const float* __restrict__ wpb,
                                                bf16* __restrict__ W2T,
                                                float* __restrict__ bias2,
                                                const float* __restrict__ bq,
                                                const float* __restrict__ bsg_attn,
                                                const float* __restrict__ bsg_tr,
                                                float* __restrict__ biasQKVG,
                                                float* __restrict__ biasSG) {
  const int blk = blockIdx.x;
  const int t = threadIdx.x;
  if (blk == 48) {
    for (int f = t; f < 64 * CZ; f += 256) {
      const int col = f >> 7, c = f & 127, b = col >> 4, h = col & 15;
      W2T[f] = __float2bfloat16(ln_z_w[b * CZ + c] * wpb[(b * CZ + c) * NHEAD + h]);
    }
    if (t < 64) {
      const int b = t >> 4, h = t & 15;
      float sum = 0.f;
      for (int c = 0; c < CZ; ++c)
        sum += ln_z_b[b * CZ + c] * wpb[(b * CZ + c) * NHEAD + h];
      bias2[t] = sum;
    }
    return;
  }
  const int g = blk * 256 + t;
  if (g < 4 * 3072) {
    const int b = g / 3072, c = g % 3072;
    biasQKVG[g] = (c < 768) ? bq[b * 768 + c] : 0.f;
  }
  if (g < 6144) {
    const int b = g / 1536, c = g % 1536;
    biasSG[g] = (c < 768) ? bsg_attn[b * 768 + c] : bsg_tr[b * 768 + c - 768];
  }
}

// ---------------- zbias: LN(z)@W2T + bias2 + beta -> bf16 [64][S][S], MFMA ----------------
__global__ __launch_bounds__(256) void zbias_kernel(const float* __restrict__ z,
                                                    const float* __restrict__ beta,
                                                    const bf16* __restrict__ W2T,
                                                    const float* __restrict__ bias2,
                                                    bf16* __restrict__ bias_all) {
  __shared__ s8v zt8[64 * 16];
  __shared__ s8v w2s[64 * 16];
  __shared__ float betas[64][17];
  __shared__ float bias2s[64];
  __shared__ bf16 obuf[64][72];
  const int t = threadIdx.x;
  const int i = blockIdx.y, j0 = blockIdx.x * 64;
#pragma unroll
  for (int q = 0; q < 4; ++q) {
    const int u = q * 256 + t;
    const int row = u >> 4, sl = u & 15;
    w2s[row * 16 + (sl ^ (row & 7))] = *(const s8v*)(W2T + row * CZ + sl * 8);
  }
  if (t < 64) bias2s[t] = bias2[t];
  {
    const int j = t >> 2, h4 = t & 3;
    const float4 bv = *(const float4*)(beta + ((size_t)i * S + j0 + j) * NHEAD + 4 * h4);
    betas[j][4 * h4 + 0] = bv.x; betas[j][4 * h4 + 1] = bv.y;
    betas[j][4 * h4 + 2] = bv.z; betas[j][4 * h4 + 3] = bv.w;
  }
  {
    const int p = t >> 2, q = t & 3;
    const float* zr = z + ((size_t)i * S + j0 + p) * CZ + q * 32;
    float vals[32];
    float sum = 0.f, sq = 0.f;
#pragma unroll
    for (int k4 = 0; k4 < 8; ++k4) {
      const float4 xv = *(const float4*)(zr + 4 * k4);
      vals[4 * k4 + 0] = xv.x; vals[4 * k4 + 1] = xv.y;
      vals[4 * k4 + 2] = xv.z; vals[4 * k4 + 3] = xv.w;
      sum += xv.x + xv.y + xv.z + xv.w;
      sq += xv.x * xv.x + xv.y * xv.y + xv.z * xv.z + xv.w * xv.w;
    }
    sum += __shfl_xor(sum, 1); sum += __shfl_xor(sum, 2);
    sq += __shfl_xor(sq, 1); sq += __shfl_xor(sq, 2);
    const float m = sum / CZ;
    const float rstd = rsqrtf(sq / CZ - m * m + EPS);
#pragma unroll
    for (int u = 0; u < 4; ++u) {
      U8 pk;
#pragma unroll
      for (int e = 0; e < 8; ++e) pk.h[e] = __float2bfloat16((vals[8 * u + e] - m) * rstd);
      const int cu = 4 * q + u;
      zt8[p * 16 + (cu ^ (p & 7))] = pk.s;
    }
  }
  __syncthreads();
  const int lane = t & 63, wid = t >> 6;
  const int wr = wid >> 1, wc = wid & 1;
  const int ln = lane & 15, lq = lane >> 4;
  f4v acc[2][2] = {};
#pragma unroll
  for (int kk = 0; kk < 4; ++kk) {
    const int sl = (lq + 4 * kk) ^ (ln & 7);
    s8v a[2], b[2];
#pragma unroll
    for (int mi = 0; mi < 2; ++mi) a[mi] = zt8[(32 * wr + 16 * mi + ln) * 16 + sl];
#pragma unroll
    for (int ni = 0; ni < 2; ++ni) b[ni] = w2s[(32 * wc + 16 * ni + ln) * 16 + sl];
#pragma unroll
    for (int mi = 0; mi < 2; ++mi)
#pragma unroll
      for (int ni = 0; ni < 2; ++ni) acc[mi][ni] = mfma16(a[mi], b[ni], acc[mi][ni]);
  }
#pragma unroll
  for (int mi = 0; mi < 2; ++mi)
#pragma unroll
    for (int ni = 0; ni < 2; ++ni) {
      const int col = 32 * wc + 16 * ni + ln;
      const int jb = 32 * wr + 16 * mi + 4 * lq;
      U4 o4;
#pragma unroll
      for (int r = 0; r < 4; ++r)
        o4.h[r] = __float2bfloat16(acc[mi][ni][r] + bias2s[col] + betas[jb + r][col & 15]);
      *(uint2*)&obuf[col][jb] = o4.u;
    }
  __syncthreads();
  {
    const int oc = t >> 2, js = (t & 3) * 16;
    bf16* dp = bias_all + (size_t)oc * S * S + (size_t)i * S + j0 + js;
    *(s8v*)dp = *(const s8v*)&obuf[oc][js];
    *(s8v*)(dp + 8) = *(const s8v*)&obuf[oc][js + 8];
  }
}

// ---------------- m97-style single-buffer gload_lds paired GEMM (amode 0) ----------------
struct Gemm2Args {
  const bf16* A0[2]; int lda0[2];
  const bf16* Bt[2];
  const float* bias[2];
  void* C[2];
  int K[2];
  int nb[2];       // valid n-block count per z
  int outMode[2];  // 0: bf16 ; 1: f32 + sigmoid
  int N[2];
  bf16* vT;        // if set: z==0 cols [1536,2304) diverted to vT[n-1536][m]
};

__global__ __launch_bounds__(256) void gemm2(Gemm2Args ga) {
  const int z = blockIdx.z;
  if ((int)blockIdx.x >= ga.nb[z]) return;
  __shared__ s8v As[1024];
  __shared__ s8v Bs[1024];
  const bf16* A0 = ga.A0[z]; const int lda0 = ga.lda0[z];
  const bf16* Bt = ga.Bt[z];
  const int K = ga.K[z], N = ga.N[z];
  const int t = threadIdx.x;
  const int lane = t & 63, wid = t >> 6;
  const int wr = wid >> 1, wc = wid & 1;
  const int ln = lane & 15, lq = lane >> 4;
  const int m0 = blockIdx.y * 128, n0 = blockIdx.x * 128;
  // per-lane global source col pre-swizzled so the linear LDS dest lands swizzled
  int rowA[4], colx[4];
#pragma unroll
  for (int q = 0; q < 4; ++q) {
    const int u = q * 256 + t, row = u >> 3, slp = u & 7;
    rowA[q] = row; colx[q] = (slp ^ (row & 7)) * 8;
  }
  f4v acc[4][4] = {};
  for (int ks = 0; ks < K; ks += 64) {
    __syncthreads();   // previous iteration's reads complete before overwrite
#pragma unroll
    for (int q = 0; q < 4; ++q) {
      gld_lds16(A0 + (size_t)(m0 + rowA[q]) * lda0 + ks + colx[q], &As[q * 256 + wid * 64]);
      gld_lds16(Bt + (size_t)(n0 + rowA[q]) * K + ks + colx[q], &Bs[q * 256 + wid * 64]);
    }
    __syncthreads();   // compiler drains vmcnt(0) here (m97 structure)
#pragma unroll
    for (int kk = 0; kk < 2; ++kk) {
      const int sl = (lq + 4 * kk) ^ (ln & 7);
      s8v a[4], b[4];
#pragma unroll
      for (int mi = 0; mi < 4; ++mi) a[mi] = As[(64 * wr + 16 * mi + ln) * 8 + sl];
#pragma unroll
      for (int ni = 0; ni < 4; ++ni) b[ni] = Bs[(64 * wc + 16 * ni + ln) * 8 + sl];
#pragma unroll
      for (int mi = 0; mi < 4; ++mi)
#pragma unroll
        for (int ni = 0; ni < 4; ++ni) acc[mi][ni] = mfma16(a[mi], b[ni], acc[mi][ni]);
    }
  }
  const bool vdiv = (ga.vT != nullptr) && (z == 0) && (n0 >= 1536) && (n0 < 2304);
  const int om = ga.outMode[z];
#pragma unroll
  for (int ni = 0; ni < 4; ++ni) {
    const int n = n0 + 64 * wc + 16 * ni + ln;
    const float bv = ga.bias[z] ? ga.bias[z][n] : 0.f;
#pragma unroll
    for (int mi = 0; mi < 4; ++mi) {
      const int mb = m0 + 64 * wr + 16 * mi + 4 * lq;
      if (vdiv) {
        U4 o4;
#pragma unroll
        for (int r = 0; r < 4; ++r) o4.h[r] = __float2bfloat16(acc[mi][ni][r] + bv);
        *(uint2*)(ga.vT + (size_t)(n - 1536) * S + mb) = o4.u;
      } else if (om == 0) {
        bf16* C = (bf16*)ga.C[z];
#pragma unroll
        for (int r = 0; r < 4; ++r)
          C[(size_t)(mb + r) * N + n] = __float2bfloat16(acc[mi][ni][r] + bv);
      } else {
        float* C = (float*)ga.C[z];
#pragma unroll
        for (int r = 0; r < 4; ++r)
          C[(size_t)(mb + r) * N + n] = sigmoidf_(acc[mi][ni][r] + bv);
      }
    }
  }
}

// ---------------- reg-staged paired GEMM with A-combine (wo/wout) ----------------
struct GemmPairArgs {
  const bf16* A0[2]; int lda0[2];
  const bf16* A1[2]; int lda1[2];
  const bf16* Bt[2];
  const float* bias[2];
  bf16* C[2];
  int K[2]; int amode[2];
};

DEV s8v combineRT(s8v x, s8v y, int amode) {
  U8 ux, uy, r;
  ux.s = x; uy.s = y;
#pragma unroll
  for (int j = 0; j < 8; ++j) {
    const float fx = __bfloat162float(ux.h[j]);
    const float fy = __bfloat162float(uy.h[j]);
    const float tt = sigmoidf_(fx);
    r.h[j] = __float2bfloat16((amode == 2 ? fx * tt : tt) * fy);
  }
  return r.s;
}

__global__ __launch_bounds__(256) void gemm_pair(GemmPairArgs ga, int N) {
  __shared__ s8v As[128 * 8];
  __shared__ s8v Bs[128 * 8];
  const int z = blockIdx.z;
  const bf16* A0 = ga.A0[z]; const int lda0 = ga.lda0[z];
  const bf16* A1 = ga.A1[z]; const int lda1 = ga.lda1[z];
  const bf16* Bt = ga.Bt[z];
  const float* bias = ga.bias[z];
  bf16* C = ga.C[z];
  const int K = ga.K[z], amode = ga.amode[z];
  const int t = threadIdx.x;
  const int lane = t & 63, wid = t >> 6;
  const int wr = wid >> 1, wc = wid & 1;
  const int ln = lane & 15, lq = lane >> 4;
  const int m0 = blockIdx.y * 128, n0 = blockIdx.x * 128;
  int rowS[4], slS[4], swz[4];
#pragma unroll
  for (int q = 0; q < 4; ++q) {
    const int u = q * 256 + t;
    rowS[q] = u >> 3; slS[q] = u & 7;
    swz[q] = rowS[q] * 8 + (slS[q] ^ (rowS[q] & 7));
  }
  f4v acc[4][4] = {};
  s8v ra[4], ra2[4], rb[4];
#pragma unroll
  for (int q = 0; q < 4; ++q) {
    ra[q] = *(const s8v*)(A0 + (size_t)(m0 + rowS[q]) * lda0 + slS[q] * 8);
    if (amode != 0) ra2[q] = *(const s8v*)(A1 + (size_t)(m0 + rowS[q]) * lda1 + slS[q] * 8);
    rb[q] = *(const s8v*)(Bt + (size_t)(n0 + rowS[q]) * K + slS[q] * 8);
  }
  for (int ks = 0;;) {
    __syncthreads();
#pragma unroll
    for (int q = 0; q < 4; ++q) {
      As[swz[q]] = (amode == 0) ? ra[q] : combineRT(ra[q], ra2[q], amode);
      Bs[swz[q]] = rb[q];
    }
    const int ksn = ks + 64;
    if (ksn < K) {
#pragma unroll
      for (int q = 0; q < 4; ++q) {
        ra[q] = *(const s8v*)(A0 + (size_t)(m0 + rowS[q]) * lda0 + ksn + slS[q] * 8);
        if (amode != 0) ra2[q] = *(const s8v*)(A1 + (size_t)(m0 + rowS[q]) * lda1 + ksn + slS[q] * 8);
        rb[q] = *(const s8v*)(Bt + (size_t)(n0 + rowS[q]) * K + ksn + slS[q] * 8);
      }
    }
    __syncthreads();
#pragma unroll
    for (int kk = 0; kk < 2; ++kk) {
      const int sl = (lq + 4 * kk) ^ (ln & 7);
      s8v a[4], b[4];
#pragma unroll
      for (int mi = 0; mi < 4; ++mi) a[mi] = As[(64 * wr + 16 * mi + ln) * 8 + sl];
#pragma unroll
      for (int ni = 0; ni < 4; ++ni) b[ni] = Bs[(64 * wc + 16 * ni + ln) * 8 + sl];
#pragma unroll
      for (int mi = 0; mi < 4; ++mi)
#pragma unroll
        for (int ni = 0; ni < 4; ++ni) acc[mi][ni] = mfma16(a[mi], b[ni], acc[mi][ni]);
    }
    ks = ksn;
    if (ks >= K) break;
  }
#pragma unroll
  for (int ni = 0; ni < 4; ++ni) {
    const int n = n0 + 64 * wc + 16 * ni + ln;
    const float bv = bias ? bias[n] : 0.f;
#pragma unroll
    for (int mi = 0; mi < 4; ++mi) {
      const int mb = m0 + 64 * wr + 16 * mi + 4 * lq;
#pragma unroll
      for (int r = 0; r < 4; ++r)
        C[(size_t)(mb + r) * N + n] = __float2bfloat16(acc[mi][ni][r] + bv);
    }
  }
}

// ---------------- flash attention: per (i-tile 64, head) — round-4 proven ----------------
__global__ __launch_bounds__(256) void flash_attn(const bf16* __restrict__ qkvg,
                                                  const bf16* __restrict__ vT,
                                                  const bf16* __restrict__ bias_all,
                                                  bf16* __restrict__ ob, int blk) {
  __shared__ s8v Qs[64 * 8];
  __shared__ s8v Ks[2][64 * 8];
  __shared__ s8v Vs[2][48 * 8];
  __shared__ s8v Bs[2][64 * 8];
  __shared__ bf16 PwB[4 * 1024];
  __shared__ float facL[4][16];
  __shared__ float linvL[4][16];
  const int t = threadIdx.x;
  const int lane = t & 63, w = t >> 6;
  const int ln = lane & 15, lq = lane >> 4;
  const int h = blockIdx.y, i0 = blockIdx.x * 64;
  const bf16* bp = bias_all + (size_t)(blk * NHEAD + h) * S * S;
  const float scale = 0.14433756729740643f;

#pragma unroll
  for (int uu = 0; uu < 2; ++uu) {
    const int u = t + 256 * uu, row = u >> 3, sl = u & 7;
    s8v qv{};
    if (sl < 6) qv = *(const s8v*)(qkvg + (size_t)(i0 + row) * 3072 + h * DH + sl * 8);
    Qs[row * 8 + (sl ^ (row & 7))] = qv;
  }

  s8v kr[2], br[2], vr0{}, vr1{};
  auto prefetch = [&](int jt) {
    const int j0 = jt * 64;
#pragma unroll
    for (int uu = 0; uu < 2; ++uu) {
      const int u = t + 256 * uu, row = u >> 3, sl = u & 7;
      s8v kv{};
      if (sl < 6) kv = *(const s8v*)(qkvg + (size_t)(j0 + row) * 3072 + 768 + h * DH + sl * 8);
      kr[uu] = kv;
      br[uu] = *(const s8v*)(bp + (size_t)(i0 + row) * S + j0 + sl * 8);
    }
    { const int d = t >> 3, sl = t & 7;
      vr0 = *(const s8v*)(vT + (size_t)(h * DH + d) * S + j0 + sl * 8); }
    if (t < 128) {
      const int u = 256 + t, d = u >> 3, sl = u & 7;
      vr1 = *(const s8v*)(vT + (size_t)(h * DH + d) * S + j0 + sl * 8);
    }
  };
  auto store_tiles = [&](int pb) {
#pragma unroll
    for (int uu = 0; uu < 2; ++uu) {
      const int u = t + 256 * uu, row = u >> 3, sl = u & 7;
      const int ph = row * 8 + (sl ^ (row & 7));
      Ks[pb][ph] = kr[uu];
      Bs[pb][ph] = br[uu];
    }
    { const int d = t >> 3, sl = t & 7;
      Vs[pb][d * 8 + (sl ^ (d & 7))] = vr0; }
    if (t < 128) {
      const int u = 256 + t, d = u >> 3, sl = u & 7;
      Vs[pb][d * 8 + (sl ^ (d & 7))] = vr1;
    }
  };

  float m_run = -3e30f, l_run = 0.f;
  f4v acc_o[3] = {};
  bf16* pw = PwB + w * 1024;

  prefetch(0);
  for (int jt = 0; jt < 16; ++jt) {
    const int pb = jt & 1;
    __syncthreads();
    store_tiles(pb);
    __syncthreads();
    if (jt < 15) prefetch(jt + 1);
    float p[4][4];
    float tmax = -3e30f;
#pragma unroll
    for (int ja = 0; ja < 4; ++ja) {
      f4v accs = {};
#pragma unroll
      for (int ks2 = 0; ks2 < 2; ++ks2) {
        const int sl = (lq + 4 * ks2) ^ (ln & 7);
        const s8v a = Ks[pb][(16 * ja + ln) * 8 + sl];
        const s8v b = Qs[(16 * w + ln) * 8 + sl];
        accs = mfma16(a, b, accs);
      }
      const int jq = 4 * ja + lq;
      const int pu = jq >> 1;
      U4 bv;
      bv.u = *(const uint2*)((const bf16*)(&Bs[pb][0]) +
                             (((16 * w + ln) * 8 + (pu ^ (ln & 7))) * 8 + (jq & 1) * 4));
#pragma unroll
      for (int r = 0; r < 4; ++r) {
        p[ja][r] = accs[r] * scale + __bfloat162float(bv.h[r]);
        tmax = fmaxf(tmax, p[ja][r]);
      }
    }
    tmax = fmaxf(tmax, __shfl_xor(tmax, 16));
    tmax = fmaxf(tmax, __shfl_xor(tmax, 32));
    const float m_new = fmaxf(m_run, tmax);
    const float fac = __expf(m_run - m_new);
    m_run = m_new;
    float psum = 0.f;
#pragma unroll
    for (int ja = 0; ja < 4; ++ja)
#pragma unroll
      for (int r = 0; r < 4; ++r) {
        p[ja][r] = __expf(p[ja][r] - m_new);
        psum += p[ja][r];
      }
    psum += __shfl_xor(psum, 16);
    psum += __shfl_xor(psum, 32);
    l_run = l_run * fac + psum;
    if (lq == 0) facL[w][ln] = fac;
#pragma unroll
    for (int ja = 0; ja < 4; ++ja) {
      const int ju = 4 * ja + lq;
      const int ph = ju ^ ((ln & 7) << 1);
      U4 pk;
#pragma unroll
      for (int r = 0; r < 4; ++r) pk.h[r] = __float2bfloat16(p[ja][r]);
      *(uint2*)(pw + ln * 64 + ph * 4) = pk.u;
    }
    asm volatile("s_waitcnt lgkmcnt(0)" ::: "memory");
    __builtin_amdgcn_sched_barrier(0);
    const float4 fv = *(const float4*)&facL[w][4 * lq];
#pragma unroll
    for (int ni = 0; ni < 3; ++ni) {
      acc_o[ni][0] *= fv.x; acc_o[ni][1] *= fv.y;
      acc_o[ni][2] *= fv.z; acc_o[ni][3] *= fv.w;
    }
#pragma unroll
    for (int ks2 = 0; ks2 < 2; ++ks2) {
      const int pu0 = (2 * lq + 8 * ks2) ^ ((ln & 7) << 1);
      const s8v pa = *(const s8v*)(pw + ln * 64 + pu0 * 4);
      const int slv = (lq + 4 * ks2) ^ (ln & 7);
#pragma unroll
      for (int ni = 0; ni < 3; ++ni) {
        const s8v vb = Vs[pb][(16 * ni + ln) * 8 + slv];
        acc_o[ni] = mfma16(pa, vb, acc_o[ni]);
      }
    }
  }
  if (lq == 0) linvL[w][ln] = 1.0f / l_run;
  asm volatile("s_waitcnt lgkmcnt(0)" ::: "memory");
  __builtin_amdgcn_sched_barrier(0);
  const float4 lv = *(const float4*)&linvL[w][4 * lq];
  const float lvr[4] = {lv.x, lv.y, lv.z, lv.w};
#pragma unroll
  for (int ni = 0; ni < 3; ++ni)
#pragma unroll
    for (int r = 0; r < 4; ++r) {
      const int m = i0 + 16 * w + 4 * lq + r;
      ob[(size_t)m * CA + h * DH + 16 * ni + ln] = __float2bfloat16(acc_o[ni][r] * lvr[r]);
    }
}

// ---------------- final (last block only): out = sgA*att + sgT*tr (f32) ----------------
__global__ __launch_bounds__(256) void ew_final(const float* __restrict__ sg,
                                                const bf16* __restrict__ att,
                                                const bf16* __restrict__ tr,
                                                float* __restrict__ out) {
  const int i = blockIdx.x * 256 + threadIdx.x;
  const int row = i / 192, col = (i % 192) * 4;
  const float4 sa = *(const float4*)(sg + (size_t)row * 6144 + col);
  const float4 st = *(const float4*)(sg + (size_t)row * 6144 + 768 + col);
  U4 av, tv;
  av.u = *(const uint2*)(att + (size_t)row * CA + col);
  tv.u = *(const uint2*)(tr + (size_t)row * CA + col);
  float4 o;
  o.x = sa.x * __bfloat162float(av.h[0]) + st.x * __bfloat162float(tv.h[0]);
  o.y = sa.y * __bfloat162float(av.h[1]) + st.y * __bfloat162float(tv.h[1]);
  o.z = sa.z * __bfloat162float(av.h[2]) + st.z * __bfloat162float(tv.h[2]);
  o.w = sa.w * __bfloat162float(av.h[3]) + st.w * __bfloat162float(tv.h[3]);
  *(float4*)(out + (size_t)row * CA + col) = o;
}

__global__ void fill_kernel(float* p, int n, float v) {
  const int i = blockIdx.x * 256 + threadIdx.x;
  if (i < n) p[i] = v;
}

extern "C" void kernel_launch(void* const* d_in, const int* in_sizes, int n_in,
                              void* d_out, int out_size, void* d_ws, size_t ws_size,
                              hipStream_t stream) {
  (void)in_sizes; (void)n_in;
  const float* a_in = (const float*)d_in[0];
  const float* s_in = (const float*)d_in[1];
  const float* z_in = (const float*)d_in[2];
  const float* beta = (const float*)d_in[3];
  const float* ln_s_w_attn = (const float*)d_in[4];
  const float* wg_attn = (const float*)d_in[5];
  const float* wb_attn = (const float*)d_in[6];
  const float* wq = (const float*)d_in[7];
  const float* bq = (const float*)d_in[8];
  const float* wk = (const float*)d_in[9];
  const float* wv = (const float*)d_in[10];
  const float* ln_z_w = (const float*)d_in[11];
  const float* ln_z_b = (const float*)d_in[12];
  const float* wpb = (const float*)d_in[13];
  const float* wgate = (const float*)d_in[14];
  const float* wo = (const float*)d_in[15];
  const float* wsg_attn = (const float*)d_in[16];
  const float* bsg_attn = (const float*)d_in[17];
  const float* ln_s_w_tr = (const float*)d_in[18];
  const float* wg_tr = (const float*)d_in[19];
  const float* wb_tr = (const float*)d_in[20];
  const float* w_swish = (const float*)d_in[21];
  const float* w_gate2 = (const float*)d_in[22];
  const float* wsg_tr = (const float*)d_in[23];
  const float* bsg_tr = (const float*)d_in[24];
  const float* w_out = (const float*)d_in[25];

  char* wp = (char*)d_ws;
  size_t used = 0;
  auto alloc = [&](size_t bytes) -> void* {
    void* p = wp + used;
    used += (bytes + 255) & ~(size_t)255;
    return p;
  };
  bf16* bias_all = (bf16*)alloc((size_t)64 * S * S * 2);
  bf16* WT_ada = (bf16*)alloc((size_t)4 * 3072 * 384 * 2);
  bf16* WT_sg = (bf16*)alloc((size_t)4 * 1536 * 384 * 2);
  bf16* WT_qkvg = (bf16*)alloc((size_t)4 * 3072 * 768 * 2);
  bf16* WT_wo = (bf16*)alloc((size_t)4 * 768 * 768 * 2);
  bf16* WT_mlp = (bf16*)alloc((size_t)4 * 3072 * 768 * 2);
  bf16* WT_wout = (bf16*)alloc((size_t)4 * 768 * 1536 * 2);
  float* biasQKVG = (float*)alloc(4 * 3072 * 4);
  float* biasSG = (float*)alloc(6144 * 4);
  bf16* W2T = (bf16*)alloc(64 * 128 * 2);
  float* bias2 = (float*)alloc(64 * 4);
  bf16* ada_all = (bf16*)alloc((size_t)S * 12288 * 2);
  float* sg_all = (float*)alloc((size_t)S * 6144 * 4);
  bf16* s_hat = (bf16*)alloc((size_t)S * CS * 2);
  bf16* s_bf = (bf16*)alloc((size_t)S * CS * 2);
  bf16* ah_attn = (bf16*)alloc((size_t)S * CA * 2);
  bf16* ah_tr = (bf16*)alloc((size_t)S * CA * 2);
  bf16* qkvg = (bf16*)alloc((size_t)S * 3072 * 2);
  bf16* vT = (bf16*)alloc((size_t)CA * S * 2);
  bf16* ob = (bf16*)alloc((size_t)S * CA * 2);
  bf16* att = (bf16*)alloc((size_t)S * CA * 2);
  bf16* swg = (bf16*)alloc((size_t)S * 3072 * 2);
  bf16* trout = (bf16*)alloc((size_t)S * CA * 2);
  if (used > ws_size) {
    fill_kernel<<<(out_size + 255) / 256, 256, 0, stream>>>((float*)d_out, out_size, 12345.0f);
    return;
  }

  const dim3 B256(256);

  prep_all<<<49, B256, 0, stream>>>(ln_z_w, ln_z_b, wpb, W2T, bias2,
                                    bq, bsg_attn, bsg_tr, biasQKVG, biasSG);

  {  // group 1: K=384, N=768 (ada x4 + sg x2)
    TGroup g{};
    g.src[0] = wg_attn;  g.dst[0] = WT_ada + (size_t)0 * 384;    g.cs[0] = ln_s_w_attn; g.dstZ[0] = 3072 * 384;
    g.src[1] = wb_attn;  g.dst[1] = WT_ada + (size_t)768 * 384;  g.cs[1] = ln_s_w_attn; g.dstZ[1] = 3072 * 384;
    g.src[2] = wg_tr;    g.dst[2] = WT_ada + (size_t)1536 * 384; g.cs[2] = ln_s_w_tr;   g.dstZ[2] = 3072 * 384;
    g.src[3] = wb_tr;    g.dst[3] = WT_ada + (size_t)2304 * 384; g.cs[3] = ln_s_w_tr;   g.dstZ[3] = 3072 * 384;
    g.src[4] = wsg_attn; g.dst[4] = WT_sg + (size_t)0 * 384;     g.cs[4] = nullptr;     g.dstZ[4] = 1536 * 384;
    g.src[5] = wsg_tr;   g.dst[5] = WT_sg + (size_t)768 * 384;   g.cs[5] = nullptr;     g.dstZ[5] = 1536 * 384;
    transpose_grp<<<dim3(24, 12, 24), B256, 0, stream>>>(g, 384, 768, CS);
  }
  {  // group 2: K=768, N=768 (wq,wk,wv,wgate,wo)
    TGroup g{};
    g.src[0] = wq;    g.dst[0] = WT_qkvg + (size_t)0 * 768;    g.dstZ[0] = 3072 * 768;
    g.src[1] = wk;    g.dst[1] = WT_qkvg + (size_t)768 * 768;  g.dstZ[1] = 3072 * 768;
    g.src[2] = wv;    g.dst[2] = WT_qkvg + (size_t)1536 * 768; g.dstZ[2] = 3072 * 768;
    g.src[3] = wgate; g.dst[3] = WT_qkvg + (size_t)2304 * 768; g.dstZ[3] = 3072 * 768;
    g.src[4] = wo;    g.dst[4] = WT_wo;                        g.dstZ[4] = 768 * 768;
    transpose_grp<<<dim3(24, 24, 20), B256, 0, stream>>>(g, 768, 768, 0);
  }
  {  // group 3: K=768, N=1536 (w_swish, w_gate2)
    TGroup g{};
    g.src[0] = w_swish; g.dst[0] = WT_mlp + (size_t)0 * 768;    g.dstZ[0] = 3072 * 768;
    g.src[1] = w_gate2; g.dst[1] = WT_mlp + (size_t)1536 * 768; g.dstZ[1] = 3072 * 768;
    transpose_grp<<<dim3(48, 24, 8), B256, 0, stream>>>(g, 768, 1536, 0);
  }
  {  // group 4: K=1536, N=768 (w_out)
    TGroup g{};
    g.src[0] = w_out; g.dst[0] = WT_wout; g.dstZ[0] = 768 * 1536;
    transpose_grp<<<dim3(24, 48, 4), B256, 0, stream>>>(g, 1536, 768, 0);
  }

  rowln_s<<<S, B256, 0, stream>>>(s_in, s_hat, s_bf);
  zbias_kernel<<<dim3(16, 1024), B256, 0, stream>>>(z_in, beta, W2T, bias2, bias_all);

  {  // hoisted: z0 ada (N=12288), z1 sg (N=6144, sigmoid, f32)
    Gemm2Args ga{};
    ga.A0[0] = s_hat; ga.lda0[0] = 384; ga.Bt[0] = WT_ada; ga.bias[0] = nullptr;
    ga.C[0] = ada_all; ga.K[0] = 384; ga.nb[0] = 96; ga.outMode[0] = 0; ga.N[0] = 12288;
    ga.A0[1] = s_bf; ga.lda0[1] = 384; ga.Bt[1] = WT_sg; ga.bias[1] = biasSG;
    ga.C[1] = sg_all; ga.K[1] = 384; ga.nb[1] = 48; ga.outMode[1] = 1; ga.N[1] = 6144;
    ga.vT = nullptr;
    gemm2<<<dim3(96, 8, 2), B256, 0, stream>>>(ga);
  }

  ln_adaln2<<<S, B256, 0, stream>>>(a_in, ada_all, ah_attn, ah_tr);
  for (int b = 0; b < NBLK; ++b) {
    {  // z0 qkvg (with fused vT divert), z1 mlp(swg)
      Gemm2Args ga{};
      ga.A0[0] = ah_attn; ga.lda0[0] = 768; ga.Bt[0] = WT_qkvg + (size_t)b * 3072 * 768;
      ga.bias[0] = biasQKVG + b * 3072; ga.C[0] = qkvg; ga.K[0] = 768; ga.nb[0] = 24;
      ga.outMode[0] = 0; ga.N[0] = 3072;
      ga.A0[1] = ah_tr; ga.lda0[1] = 768; ga.Bt[1] = WT_mlp + (size_t)b * 3072 * 768;
      ga.bias[1] = nullptr; ga.C[1] = swg; ga.K[1] = 768; ga.nb[1] = 24;
      ga.outMode[1] = 0; ga.N[1] = 3072;
      ga.vT = vT;
      gemm2<<<dim3(24, 8, 2), B256, 0, stream>>>(ga);
    }
    flash_attn<<<dim3(16, 16), B256, 0, stream>>>(qkvg, vT, bias_all, ob, b);
    {  // z0 att = (sig(gate)*ob)@wo ; z1 trout = swiglu(swg)@w_out
      GemmPairArgs ga{};
      ga.A0[0] = qkvg + 2304; ga.lda0[0] = 3072; ga.A1[0] = ob; ga.lda1[0] = 768;
      ga.Bt[0] = WT_wo + (size_t)b * 768 * 768; ga.bias[0] = nullptr;
      ga.C[0] = att; ga.K[0] = 768; ga.amode[0] = 1;
      ga.A0[1] = swg; ga.lda0[1] = 3072; ga.A1[1] = swg + 1536; ga.lda1[1] = 3072;
      ga.Bt[1] = WT_wout + (size_t)b * 768 * 1536; ga.bias[1] = nullptr;
      ga.C[1] = trout; ga.K[1] = 1536; ga.amode[1] = 2;
      gemm_pair<<<dim3(6, 8, 2), B256, 0, stream>>>(ga, 768);
    }
    if (b < NBLK - 1) {
      final_adaln<<<S, B256, 0, stream>>>(sg_all + (size_t)b * 1536, att, trout,
                                          ada_all + (size_t)(b + 1) * 3072, ah_attn, ah_tr);
    } else {
      ew_final<<<768, B256, 0, stream>>>(sg_all + (size_t)b * 1536, att, trout, (float*)d_out);
    }
  }
}